// Round 5
// baseline (87.934 us; speedup 1.0000x reference)
//
#include <hip/hip_runtime.h>
#include <hip/hip_bf16.h>

#define B_SZ 32
#define L_SZ 512
#define D_SZ 256
#define PHON_PER_WAVE 2
#define PHON_BLOCKS (B_SZ * L_SZ / (4 * PHON_PER_WAVE))  // 2048: 4 waves/blk, 2 phonemes/wave
#define CUM_STRIDE 520                                    // ints per batch row in ws (16B-aligned)
#define WS_NEEDED (B_SZ * CUM_STRIDE * 4)

// clang-native vector types: __builtin_nontemporal_* requires real vector types,
// not HIP_vector_type classes.
typedef float  f4 __attribute__((ext_vector_type(4)));
typedef int    i4 __attribute__((ext_vector_type(4)));

// ---------------- Kernel 1: per-batch inclusive cumsum of durations → ws ----
// 4 blocks x 512 threads; one wave per batch row.
// cum[b*CUM_STRIDE + i] = sum(dur[b][0..i]) inclusive, i in [0,512).
__global__ void __launch_bounds__(512)
scan_kernel(const int* __restrict__ durations, int* __restrict__ cum) {
    const int lane = threadIdx.x & 63;
    const int wv   = threadIdx.x >> 6;        // 0..7
    const int b    = blockIdx.x * 8 + wv;     // 4 blocks * 8 waves = 32 rows

    const i4* drow = (const i4*)(durations + b * L_SZ);
    const i4 a = drow[lane * 2];
    const i4 c = drow[lane * 2 + 1];

    // local inclusive sums of the 8 elements this lane owns
    const int s1 = a.x;
    const int s2 = s1 + a.y;
    const int s3 = s2 + a.z;
    const int s4 = s3 + a.w;
    const int s5 = s4 + c.x;
    const int s6 = s5 + c.y;
    const int s7 = s6 + c.z;
    const int s8 = s7 + c.w;

    // exclusive scan of per-lane totals across the wave
    int ex = s8;
    #pragma unroll
    for (int off = 1; off < 64; off <<= 1) {
        const int t = __shfl_up(ex, off, 64);
        if (lane >= off) ex += t;
    }
    ex -= s8;                                  // exclusive prefix of this lane

    i4* crow = (i4*)(cum + b * CUM_STRIDE);
    i4 o1, o2;
    o1.x = ex + s1; o1.y = ex + s2; o1.z = ex + s3; o1.w = ex + s4;
    o2.x = ex + s5; o2.y = ex + s6; o2.z = ex + s7; o2.w = ex + s8;
    crow[lane * 2]     = o1;
    crow[lane * 2 + 1] = o2;
}

// ---------------- Kernel 2: streaming copy driven by precomputed cumsum -----
// One wave per 2 phonemes (b, l0), (b, l0+1):
//   1. issue both 1KB hidden-row loads (nontemporal: read-once)
//   2. 4 uniform dword loads from ws: cum[l0-1], cum[l0], cum[l0+1], cum[511]
//      -> start0/d0/start1/d1/total with NO per-wave scan
//   3. d0+d1 coalesced 1KB nontemporal stores
//   4. wave w zeroes pad frames t = total + w + k*256 (< maxT)
__global__ void __launch_bounds__(256)
lr_copy_kernel(const float* __restrict__ hidden,
               const int* __restrict__ cum,
               float* __restrict__ out,
               int maxT) {
    const int tid  = threadIdx.x;
    const int lane = tid & 63;
    const int wave = tid >> 6;

    const int wid = blockIdx.x * 4 + wave;
    const int b   = wid >> 8;
    const int w   = wid & 255;
    const int l0  = w * 2;

    // issue hidden loads first — independent of everything else
    const f4* src0 = (const f4*)(hidden + ((size_t)(b * L_SZ + l0)) * D_SZ);
    const f4 v0 = __builtin_nontemporal_load(src0 + lane);
    const f4 v1 = __builtin_nontemporal_load(src0 + lane + 64);

    // cumsum lookups (wave-uniform addresses, broadcast loads)
    const int* crow = cum + b * CUM_STRIDE;
    const int start0 = (l0 == 0) ? 0 : crow[l0 - 1];
    const int c0     = crow[l0];       // inclusive through l0
    const int c1     = crow[l0 + 1];   // inclusive through l0+1
    const int total  = crow[511];

    const int d0     = c0 - start0;
    const int start1 = c0;
    const int d1     = c1 - c0;

    f4* dst0 = (f4*)(out + ((size_t)b * maxT + start0) * D_SZ) + lane;
    f4* dst1 = (f4*)(out + ((size_t)b * maxT + start1) * D_SZ) + lane;
    #pragma unroll
    for (int j = 0; j < 7; ++j) {          // MAX_DUR-1 = 7 possible copies
        if (j < d0) __builtin_nontemporal_store(v0, dst0 + j * 64);
        if (j < d1) __builtin_nontemporal_store(v1, dst1 + j * 64);
    }

    // zero-pad tail: wave w handles frames total + w, total + w + 256, ...
    const f4 z = (f4){0.f, 0.f, 0.f, 0.f};
    for (int t = total + w; t < maxT; t += 256) {
        f4* dst = (f4*)(out + ((size_t)b * maxT + t) * D_SZ);
        __builtin_nontemporal_store(z, dst + lane);
    }
}

// ---------------- Fallback: single-kernel path (ws too small) ---------------
__global__ void __launch_bounds__(256)
lr_kernel(const float* __restrict__ hidden,
          const int* __restrict__ durations,
          float* __restrict__ out,
          int maxT) {
    const int tid  = threadIdx.x;
    const int lane = tid & 63;
    const int wave = tid >> 6;

    const int wid = blockIdx.x * 4 + wave;
    const int b   = wid >> 8;
    const int w   = wid & 255;
    const int l0  = w * 2;

    const f4* src0 = (const f4*)(hidden + ((size_t)(b * L_SZ + l0)) * D_SZ);
    const f4 v0 = __builtin_nontemporal_load(src0 + lane);
    const f4 v1 = __builtin_nontemporal_load(src0 + lane + 64);

    const i4* drow = (const i4*)(durations + b * L_SZ);
    const i4 a = drow[lane * 2];
    const i4 c = drow[lane * 2 + 1];

    const int base = lane * 8;
    int p = 0;
    p += ((base + 0 < l0) ? a.x : 0) + (a.x << 16);
    p += ((base + 1 < l0) ? a.y : 0) + (a.y << 16);
    p += ((base + 2 < l0) ? a.z : 0) + (a.z << 16);
    p += ((base + 3 < l0) ? a.w : 0) + (a.w << 16);
    p += ((base + 4 < l0) ? c.x : 0) + (c.x << 16);
    p += ((base + 5 < l0) ? c.y : 0) + (c.y << 16);
    p += ((base + 6 < l0) ? c.z : 0) + (c.z << 16);
    p += ((base + 7 < l0) ? c.w : 0) + (c.w << 16);
    #pragma unroll
    for (int off = 32; off; off >>= 1) p += __shfl_xor(p, off, 64);
    const int start0 = p & 0xffff;
    const int total  = ((unsigned)p) >> 16;

    const int k = l0 & 7;
    const int p0 = (k < 4) ? (k == 0 ? a.x : a.z) : (k == 4 ? c.x : c.z);
    const int p1 = (k < 4) ? (k == 0 ? a.y : a.w) : (k == 4 ? c.y : c.w);
    const int d0 = __shfl(p0, l0 >> 3, 64);
    const int d1 = __shfl(p1, l0 >> 3, 64);
    const int start1 = start0 + d0;

    f4* dst0 = (f4*)(out + ((size_t)b * maxT + start0) * D_SZ) + lane;
    f4* dst1 = (f4*)(out + ((size_t)b * maxT + start1) * D_SZ) + lane;
    #pragma unroll
    for (int j = 0; j < 7; ++j) {
        if (j < d0) __builtin_nontemporal_store(v0, dst0 + j * 64);
        if (j < d1) __builtin_nontemporal_store(v1, dst1 + j * 64);
    }

    const f4 z = (f4){0.f, 0.f, 0.f, 0.f};
    for (int t = total + w; t < maxT; t += 256) {
        f4* dst = (f4*)(out + ((size_t)b * maxT + t) * D_SZ);
        __builtin_nontemporal_store(z, dst + lane);
    }
}

extern "C" void kernel_launch(void* const* d_in, const int* in_sizes, int n_in,
                              void* d_out, int out_size, void* d_ws, size_t ws_size,
                              hipStream_t stream) {
    const float* hidden = (const float*)d_in[0];
    const int* durations = (const int*)d_in[1];
    float* out = (float*)d_out;

    const int maxT = out_size / (B_SZ * D_SZ);

    if (ws_size >= (size_t)WS_NEEDED && d_ws != nullptr) {
        int* cum = (int*)d_ws;
        scan_kernel<<<4, 512, 0, stream>>>(durations, cum);
        lr_copy_kernel<<<PHON_BLOCKS, 256, 0, stream>>>(hidden, cum, out, maxT);
    } else {
        lr_kernel<<<PHON_BLOCKS, 256, 0, stream>>>(hidden, durations, out, maxT);
    }
}

// Round 6
// 83.783 us; speedup vs baseline: 1.0496x; 1.0496x over previous
//
#include <hip/hip_runtime.h>

#define B_SZ 32
#define L_SZ 512
#define D_SZ 256
#define P_PER_WAVE 8                              // phonemes per wave
#define WAVES_TOTAL (B_SZ * L_SZ / P_PER_WAVE)    // 2048 waves
#define BLOCKS (WAVES_TOTAL / 4)                  // 512 blocks x 4 waves

// clang-native vector types (required by __builtin_nontemporal_*)
typedef float f4 __attribute__((ext_vector_type(4)));
typedef int   i4 __attribute__((ext_vector_type(4)));

// One wave owns 8 consecutive phoneme rows [l0, l0+8) of batch b and writes
// a single contiguous output span [start, start+sum(d)) — per-wave linear
// store stream (DRAM row locality, mimics the 6.2 TB/s fill), vs the old
// 8192x 7KB scattered granules.
//   - 8x 1KB hidden-row loads (NT, read-once; independent of the scan, so
//     they hoist above it and hide its latency)
//   - one packed shfl_xor reduction: low 16b = prefix sum over lanes < g,
//     high 16b = row total (sums < 3584, no carry)
//   - ONE shfl of a 24-bit-packed value (8 durs x 3 bits, MAX_DUR-1=7 fits)
//     delivers all 8 per-row durations
//   - plain (cached) stores: L2 write-coalescing reorders the writeback
//     stream like the fill's
//   - pad: the 64 waves of batch b zero frames total+g, total+g+64, ...
__global__ void __launch_bounds__(256)
lr_kernel(const float* __restrict__ hidden,
          const int* __restrict__ durations,
          float* __restrict__ out,
          int maxT) {
    const int lane = threadIdx.x & 63;
    const int wv   = threadIdx.x >> 6;
    const int wid  = blockIdx.x * 4 + wv;      // 0 .. 2047
    const int b    = wid >> 6;                 // 64 waves per batch row
    const int g    = wid & 63;                 // group index within the row
    const int l0   = g * P_PER_WAVE;

    // payload: 8 consecutive hidden rows, 1KB each (contiguous 8KB)
    const f4* src = (const f4*)(hidden + ((size_t)(b * L_SZ + l0)) * D_SZ) + lane;
    f4 v[8];
    #pragma unroll
    for (int r = 0; r < 8; ++r) v[r] = __builtin_nontemporal_load(src + r * 64);

    // duration row: lane i holds durs[8i .. 8i+7]
    const i4* drow = (const i4*)(durations + b * L_SZ);
    const i4 a = drow[lane * 2];
    const i4 c = drow[lane * 2 + 1];
    const int s = a.x + a.y + a.z + a.w + c.x + c.y + c.z + c.w;   // <= 56
    const int packed = a.x | (a.y << 3) | (a.z << 6) | (a.w << 9)
                     | (c.x << 12) | (c.y << 15) | (c.z << 18) | (c.w << 21);

    // low 16: sum of full lanes i < g  (group base is lane-aligned: l0 = 8g)
    // high 16: full row total
    int p = ((lane < g) ? s : 0) + (s << 16);
    #pragma unroll
    for (int off = 32; off; off >>= 1) p += __shfl_xor(p, off, 64);
    int start       = p & 0xffff;              // sum durs[0 .. l0-1]
    const int total = ((unsigned)p) >> 16;     // sum durs[0 .. 511]

    const int pk = __shfl(packed, g, 64);      // this wave's 8 durations

    float* obase = out + (size_t)b * maxT * D_SZ;
    #pragma unroll
    for (int r = 0; r < 8; ++r) {
        const int d = (pk >> (3 * r)) & 7;     // duration of row l0+r
        f4* dst = (f4*)(obase + (size_t)start * D_SZ) + lane;
        #pragma unroll
        for (int j = 0; j < 7; ++j)            // MAX_DUR-1 = 7
            if (j < d) dst[j * 64] = v[r];     // wave-uniform branch
        start += d;
    }

    // zero-pad tail of batch b
    const f4 z = (f4){0.f, 0.f, 0.f, 0.f};
    for (int t = total + g; t < maxT; t += 64) {
        f4* dst = (f4*)(obase + (size_t)t * D_SZ) + lane;
        *dst = z;
    }
}

extern "C" void kernel_launch(void* const* d_in, const int* in_sizes, int n_in,
                              void* d_out, int out_size, void* d_ws, size_t ws_size,
                              hipStream_t stream) {
    const float* hidden = (const float*)d_in[0];
    const int* durations = (const int*)d_in[1];
    float* out = (float*)d_out;

    const int maxT = out_size / (B_SZ * D_SZ);

    lr_kernel<<<BLOCKS, 256, 0, stream>>>(hidden, durations, out, maxT);
}